// Round 6
// baseline (464.505 us; speedup 1.0000x reference)
//
#include <hip/hip_runtime.h>

// Cumulative average along last axis: y[..., t] = cumsum(x)[..., t] / (t+1)
// x: fp32, shape (8, 512, 16384) -> 4096 independent rows of T=16384.
//
// v6: TWO COPY-SHAPED PASSES (kill the serial row carry).
// v2-v5 (4 different single-pass structures) all pinned at ~170us / 2.3TB/s
// while the harness's write-only fill hits 6.5TB/s at 10% occupancy: the
// invariant was the serial carry chain across each row gating every store.
//   Pass A: per-1024-chunk sums -> d_ws (pure read stream + shfl reduce).
//   Pass B: each block = 4 INDEPENDENT chunks: offset comes from the row's
//           16 partials (uniform scalar loads, predicated prefix), one-shot
//           wave scan per chunk, one barrier, rcp-divide, NT stores.
//           No inter-chunk dependency anywhere -> pure burst, blocks retire
//           immediately, copy-like streaming. Input (exactly L3-sized) is
//           hot from pass A -> B's reads largely L3 hits.
// Kernel boundary on the stream = device-wide fence (cross-XCD safe).

#define ROW_T   16384
#define CHUNK   1024
#define NCH     (ROW_T / CHUNK)      // 16 chunks per row
#define KPB     4                    // chunks per block (both passes)
#define THREADS 256
#define NWAVES  (THREADS / 64)

typedef float f32x4 __attribute__((ext_vector_type(4)));

// ---------------- Pass A: chunk sums -> part[row*NCH + chunk] ----------------
__global__ __launch_bounds__(THREADS)
void chunksum_kernel(const float* __restrict__ x, float* __restrict__ part) {
    const int  bid   = blockIdx.x;                 // covers KPB chunks
    const long gbase = (long)bid * (KPB * CHUNK);
    const int  pbase = bid * KPB;
    const int  tid   = threadIdx.x;
    const int  lane  = tid & 63;
    const int  wave  = tid >> 6;

    __shared__ float wsum[KPB][NWAVES];

    f32x4 v[KPB];
    #pragma unroll
    for (int k = 0; k < KPB; ++k)
        v[k] = *reinterpret_cast<const f32x4*>(x + gbase + k * CHUNK + tid * 4);

    float ts[KPB];
    #pragma unroll
    for (int k = 0; k < KPB; ++k)
        ts[k] = (v[k].x + v[k].y) + (v[k].z + v[k].w);

    // 4 interleaved butterfly reductions (independent -> ILP)
    #pragma unroll
    for (int d = 1; d < 64; d <<= 1) {
        #pragma unroll
        for (int k = 0; k < KPB; ++k)
            ts[k] += __shfl_xor(ts[k], d, 64);
    }

    if (lane == 0) {
        #pragma unroll
        for (int k = 0; k < KPB; ++k) wsum[k][wave] = ts[k];
    }
    __syncthreads();

    if (tid < KPB) {
        float s = 0.0f;
        #pragma unroll
        for (int w = 0; w < NWAVES; ++w) s += wsum[tid][w];
        part[pbase + tid] = s;
    }
}

// ---------------- Pass B: independent chunk scans + emit ----------------
__global__ __launch_bounds__(THREADS)
void scanout_kernel(const float* __restrict__ x, const float* __restrict__ part,
                    float* __restrict__ y) {
    const int  bid   = blockIdx.x;
    const long gbase = (long)bid * (KPB * CHUNK);
    const int  c0    = (bid * KPB) & (NCH - 1);    // first chunk idx in row
    const int  prow  = (bid * KPB) & ~(NCH - 1);   // row * NCH
    const int  tid   = threadIdx.x;
    const int  lane  = tid & 63;
    const int  wave  = tid >> 6;

    __shared__ float wsum[KPB][NWAVES];

    // Issue the data loads FIRST so they are in flight during offset calc
    f32x4 v[KPB];
    #pragma unroll
    for (int k = 0; k < KPB; ++k)
        v[k] = *reinterpret_cast<const f32x4*>(x + gbase + k * CHUNK + tid * 4);

    // Row's 16 chunk sums: uniform addresses -> scalar loads, all independent
    float pall[NCH];
    #pragma unroll
    for (int c = 0; c < NCH; ++c) pall[c] = part[prow + c];

    // Exclusive chunk offsets, predicated (no runtime-indexed array access)
    float offk[KPB];
    #pragma unroll
    for (int k = 0; k < KPB; ++k) {
        float o = 0.0f;
        #pragma unroll
        for (int c = 0; c < NCH; ++c) o += (c < c0 + k) ? pall[c] : 0.0f;
        offk[k] = o;
    }

    // 4 independent one-shot wave scans, interleaved
    float ts[KPB], inc[KPB];
    #pragma unroll
    for (int k = 0; k < KPB; ++k) {
        ts[k]  = (v[k].x + v[k].y) + (v[k].z + v[k].w);
        inc[k] = ts[k];
    }
    #pragma unroll
    for (int d = 1; d < 64; d <<= 1) {
        #pragma unroll
        for (int k = 0; k < KPB; ++k) {
            float n = __shfl_up(inc[k], d, 64);
            if (lane >= d) inc[k] += n;
        }
    }

    if (lane == 63) {
        #pragma unroll
        for (int k = 0; k < KPB; ++k) wsum[k][wave] = inc[k];
    }
    __syncthreads();

    #pragma unroll
    for (int k = 0; k < KPB; ++k) {
        float woff = 0.0f;
        #pragma unroll
        for (int w = 0; w < NWAVES; ++w)
            woff += (w < wave) ? wsum[k][w] : 0.0f;

        float ex = offk[k] + woff + (inc[k] - ts[k]);

        // position of this thread's first element within the row
        const float pf = (float)((c0 + k) * CHUNK + tid * 4);

        float s0 = ex + v[k].x;
        float s1 = s0 + v[k].y;
        float s2 = s1 + v[k].z;
        float s3 = s2 + v[k].w;

        f32x4 o;
        o.x = s0 * __builtin_amdgcn_rcpf(pf + 1.0f);
        o.y = s1 * __builtin_amdgcn_rcpf(pf + 2.0f);
        o.z = s2 * __builtin_amdgcn_rcpf(pf + 3.0f);
        o.w = s3 * __builtin_amdgcn_rcpf(pf + 4.0f);

        __builtin_nontemporal_store(o, reinterpret_cast<f32x4*>(y + gbase + k * CHUNK + tid * 4));
    }
}

extern "C" void kernel_launch(void* const* d_in, const int* in_sizes, int n_in,
                              void* d_out, int out_size, void* d_ws, size_t ws_size,
                              hipStream_t stream) {
    const float* x    = (const float*)d_in[0];
    float*       y    = (float*)d_out;
    float*       part = (float*)d_ws;              // needs 256 KiB

    const long total = in_sizes[0];                // 67,108,864 elements
    const int  nblk  = (int)(total / (KPB * CHUNK));   // 16384

    hipLaunchKernelGGL(chunksum_kernel, dim3(nblk), dim3(THREADS), 0, stream, x, part);
    hipLaunchKernelGGL(scanout_kernel,  dim3(nblk), dim3(THREADS), 0, stream, x, part, y);
}